// Round 7
// baseline (116.969 us; speedup 1.0000x reference)
//
#include <hip/hip_runtime.h>
#include <hip/hip_bf16.h>

#define NN 8192
#define CC 256
// exp(x/0.01) = exp2(x * 100 * log2(e))
#define ESCALE 144.26950408889634f

typedef __attribute__((ext_vector_type(8))) short short8;
typedef __attribute__((ext_vector_type(16))) float f32x16;

typedef __attribute__((address_space(3))) unsigned int lds_u32;
typedef __attribute__((address_space(1))) const unsigned int glb_u32;

__device__ __forceinline__ void gload16(const ushort* g, ushort* l) {
  __builtin_amdgcn_global_load_lds((glb_u32*)(const void*)g, (lds_u32*)(void*)l, 16, 0, 0);
}

// ---------------- per-channel sum of squares (partials) ----------------
__global__ void colsumsq_kernel(const float* __restrict__ x, const float* __restrict__ y,
                                float* __restrict__ part) {
  const int b = blockIdx.x, t = threadIdx.x;
  const float* src = (b < 256) ? x : y;
  const int bb = b & 255;
  float s = 0.f;
#pragma unroll 4
  for (int r = 0; r < 32; ++r) {
    float v = src[(size_t)(bb * 32 + r) * CC + t];
    s = fmaf(v, v, s);
  }
  part[b * CC + t] = s;
}

// one wave per output norm: 512 outputs = 128 blocks x 4 waves
__global__ void finnorm_kernel(const float* __restrict__ part, float* __restrict__ inv_n) {
  const int g = blockIdx.x * 4 + (threadIdx.x >> 6);  // 0..511
  const int lane = threadIdx.x & 63;
  const int c = g & 255, T = g >> 8;
  float s = 0.f;
#pragma unroll
  for (int r = 0; r < 4; ++r)
    s += part[(size_t)((T << 8) + lane * 4 + r) * CC + c];
#pragma unroll
  for (int d = 1; d < 64; d <<= 1) s += __shfl_xor(s, d);
  if (lane == 0) inv_n[g] = 1.0f / sqrtf(s);
}

// ---------------- normalize + convert to bf16 (x and y fused) ----------------
__global__ void normconv_kernel(const float* __restrict__ x, const float* __restrict__ y,
                                const float* __restrict__ inv_n,
                                ushort* __restrict__ xnb, ushort* __restrict__ ynb) {
  int b = blockIdx.x;
  const float* src; ushort* dst; const float* inv;
  if (b < 2048) { src = x; dst = xnb; inv = inv_n; }
  else          { src = y; dst = ynb; inv = inv_n + 256; b -= 2048; }
  const int idx = (b * 256 + threadIdx.x) * 4;
  const float4 v = *(const float4*)(src + idx);
  const int c = idx & (CC - 1);
  __hip_bfloat16 h0 = __float2bfloat16(v.x * inv[c + 0]);
  __hip_bfloat16 h1 = __float2bfloat16(v.y * inv[c + 1]);
  __hip_bfloat16 h2 = __float2bfloat16(v.z * inv[c + 2]);
  __hip_bfloat16 h3 = __float2bfloat16(v.w * inv[c + 3]);
  ushort4 o;
  o.x = *(ushort*)&h0; o.y = *(ushort*)&h1; o.z = *(ushort*)&h2; o.w = *(ushort*)&h3;
  *(ushort4*)(dst + idx) = o;
}

// ---------------- main GEMM + fused epilogue ----------------
// 128x128 tile, 4 waves (2x2), BK=32, mfma_f32_32x32x16_bf16.
// Double-buffered LDS; per K-iter: issue next-tile global_load_lds FIRST,
// then ds_read+MFMA current, then ONE __syncthreads (certifies next tile).
// LDS slot-XOR swizzle (slot ^= row&3 in 16B granules): linear gload dest +
// inverse-permuted global source + swizzled ds_read (rule: both sides).
__global__ __launch_bounds__(256, 2)
void gemm_corr_kernel(const ushort* __restrict__ Xn, const ushort* __restrict__ Yn,
                      float* __restrict__ corr_top,     // [256][NN]
                      float* __restrict__ rowmax_part,  // [64][NN]  idx cb*NN + i
                      float* __restrict__ colsum_part)  // [64][NN]  idx rb*NN + j
{
  const int cb = blockIdx.x, rb = blockIdx.y;
  const int tid = threadIdx.x;
  const int lane = tid & 63, wid = tid >> 6;
  const int wr = wid >> 1, wc = wid & 1;       // 2x2 wave grid, wave tile 64x64
  const int cl = lane & 31, hi = lane >> 5;

  __shared__ __align__(16) ushort As[2][4096];   // [buf][row*32 + k], swizzled
  __shared__ __align__(16) ushort Bs[2][4096];
  __shared__ float redmax[2][128];
  __shared__ float redsum[2][128];

  f32x16 acc[2][2];
#pragma unroll
  for (int mi = 0; mi < 2; ++mi)
#pragma unroll
    for (int ni = 0; ni < 2; ++ni)
#pragma unroll
      for (int r = 0; r < 16; ++r) acc[mi][ni][r] = 0.f;

  // --- staging map: granule G = half*256 + wid*64 + lane holds
  //     (row = G>>2, slot_log = (G&3)^((G>>2)&3)); source pre-permuted.
  const int srow = wid * 16 + (lane >> 2);                 // row in 64-half
  const int sp = (lane & 3) ^ ((lane >> 2) & 3);           // permuted slot
  const size_t gA0 = (size_t)(rb * 128 + srow) * CC + sp * 8;
  const size_t gA1 = (size_t)(rb * 128 + 64 + srow) * CC + sp * 8;
  const size_t gB0 = (size_t)(cb * 128 + srow) * CC + sp * 8;
  const size_t gB1 = (size_t)(cb * 128 + 64 + srow) * CC + sp * 8;

  auto stage = [&](int c, int kt) {
    const int ko = kt * 32;
    gload16(Xn + gA0 + ko, &As[c][wid * 512]);
    gload16(Xn + gA1 + ko, &As[c][2048 + wid * 512]);
    gload16(Yn + gB0 + ko, &Bs[c][wid * 512]);
    gload16(Yn + gB1 + ko, &Bs[c][2048 + wid * 512]);
  };

  // --- swizzled fragment read: row = base+cl, slot_log = 2t+hi
  auto rdfrag = [&](const ushort* S, int rowbase, int t) -> short8 {
    const int row = rowbase + cl;
    const int sph = (2 * t + hi) ^ (cl & 3);
    return *(const short8*)(&S[row * 32 + sph * 8]);
  };

  stage(0, 0);
  __syncthreads();

  int cur = 0;
#pragma unroll
  for (int kk = 0; kk < 8; ++kk) {
    if (kk < 7) stage(cur ^ 1, kk + 1);        // issue next-tile DMA first
#pragma unroll
    for (int t = 0; t < 2; ++t) {
      short8 af0 = rdfrag(As[cur], wr * 64, t);
      short8 af1 = rdfrag(As[cur], wr * 64 + 32, t);
      short8 bf0 = rdfrag(Bs[cur], wc * 64, t);
      short8 bf1 = rdfrag(Bs[cur], wc * 64 + 32, t);
      acc[0][0] = __builtin_amdgcn_mfma_f32_32x32x16_bf16(af0, bf0, acc[0][0], 0, 0, 0);
      acc[0][1] = __builtin_amdgcn_mfma_f32_32x32x16_bf16(af0, bf1, acc[0][1], 0, 0, 0);
      acc[1][0] = __builtin_amdgcn_mfma_f32_32x32x16_bf16(af1, bf0, acc[1][0], 0, 0, 0);
      acc[1][1] = __builtin_amdgcn_mfma_f32_32x32x16_bf16(af1, bf1, acc[1][1], 0, 0, 0);
    }
    __syncthreads();                           // certifies next buf + read-done
    cur ^= 1;
  }

  // ---- epilogue ----
  // C/D map (32x32): row = mi*32 + (reg&3) + 8*(reg>>2) + 4*hi ; col = ni*32 + cl
  if (rb < 2) {
#pragma unroll
    for (int mi = 0; mi < 2; ++mi)
#pragma unroll
      for (int ni = 0; ni < 2; ++ni) {
        const int colg = cb * 128 + wc * 64 + ni * 32 + cl;
#pragma unroll
        for (int reg = 0; reg < 16; ++reg) {
          const int rowg = rb * 128 + wr * 64 + mi * 32 + (reg & 3) + 8 * (reg >> 2) + 4 * hi;
          corr_top[(size_t)rowg * NN + colg] = acc[mi][ni][reg];
        }
      }
  }

  // row max over this block's 128 columns
#pragma unroll
  for (int mi = 0; mi < 2; ++mi)
#pragma unroll
    for (int reg = 0; reg < 16; ++reg) {
      float t = fmaxf(acc[mi][0][reg], acc[mi][1][reg]);
      t = fmaxf(t, __shfl_xor(t, 1));
      t = fmaxf(t, __shfl_xor(t, 2));
      t = fmaxf(t, __shfl_xor(t, 4));
      t = fmaxf(t, __shfl_xor(t, 8));
      t = fmaxf(t, __shfl_xor(t, 16));
      if (cl == 0)
        redmax[wc][wr * 64 + mi * 32 + (reg & 3) + 8 * (reg >> 2) + 4 * hi] = t;
    }
  __syncthreads();
  if (tid < 128)
    rowmax_part[(size_t)cb * NN + rb * 128 + tid] = fmaxf(redmax[0][tid], redmax[1][tid]);
  __syncthreads();

  // column sum of exp over this block's 128 rows
#pragma unroll
  for (int ni = 0; ni < 2; ++ni) {
    float s = 0.f;
#pragma unroll
    for (int mi = 0; mi < 2; ++mi)
#pragma unroll
      for (int reg = 0; reg < 16; ++reg)
        s += exp2f(acc[mi][ni][reg] * ESCALE);
    s += __shfl_xor(s, 32);
    if (hi == 0) redsum[wr][wc * 64 + ni * 32 + cl] = s;
  }
  __syncthreads();
  if (tid < 128)
    colsum_part[(size_t)rb * NN + cb * 128 + tid] = redsum[0][tid] + redsum[1][tid];
}

// ---------------- fused reductions: thread per output, coalesced ----------------
__global__ void reduce_both_kernel(const float* __restrict__ rowmax_part,
                                   const float* __restrict__ colsum_part,
                                   float* __restrict__ out, float* __restrict__ inv_s) {
  const int g = blockIdx.x * 256 + threadIdx.x;   // [0, 16384)
  if (g < 8192) {
    float m = -3.4e38f;
#pragma unroll
    for (int b = 0; b < 64; ++b) m = fmaxf(m, rowmax_part[(size_t)b * NN + g]);
    out[256 + g] = m;
  } else {
    const int j = g - 8192;
    float s = 0.f;
#pragma unroll
    for (int b = 0; b < 64; ++b) s += colsum_part[(size_t)b * NN + j];
    inv_s[j] = 1.0f / s;
  }
}

// ---------------- warped color: one block per k<256 (reads normalized ynb) ----
__global__ void warped_kernel(const float* __restrict__ corr_top, const float* __restrict__ inv_s,
                              const ushort* __restrict__ ynb, float* __restrict__ out) {
  const int k = blockIdx.x;
  const int tid = threadIdx.x;
  float p = 0.f;
  for (int j = tid; j < NN; j += 256) {
    float e = exp2f(corr_top[(size_t)k * NN + j] * ESCALE);
    float yv = __uint_as_float((unsigned)ynb[(size_t)j * CC + k] << 16);
    p += e * inv_s[j] * yv;
  }
#pragma unroll
  for (int d = 1; d < 64; d <<= 1) p += __shfl_xor(p, d);
  __shared__ float wsum[4];
  if ((tid & 63) == 0) wsum[tid >> 6] = p;
  __syncthreads();
  if (tid == 0) out[k] = wsum[0] + wsum[1] + wsum[2] + wsum[3];
}

extern "C" void kernel_launch(void* const* d_in, const int* in_sizes, int n_in,
                              void* d_out, int out_size, void* d_ws, size_t ws_size,
                              hipStream_t stream) {
  const float* x = (const float*)d_in[0];
  const float* y = (const float*)d_in[1];
  float* out = (float*)d_out;
  char* ws = (char*)d_ws;

  ushort* xnb        = (ushort*)(ws);                        // 4 MB
  ushort* ynb        = (ushort*)(ws + (4u << 20));           // 4 MB
  float*  corr_top   = (float*)(ws + (8u << 20));            // 8 MB
  float*  rowmax_prt = (float*)(ws + (16u << 20));           // 2 MB
  float*  colsum_prt = (float*)(ws + (18u << 20));           // 2 MB
  float*  part       = (float*)(ws + (20u << 20));           // 512 KB
  float*  inv_n      = (float*)(ws + (20u << 20) + 524288);  // 2 KB
  float*  inv_s      = (float*)(ws + (20u << 20) + 524288 + 4096); // 32 KB

  colsumsq_kernel<<<512, 256, 0, stream>>>(x, y, part);
  finnorm_kernel<<<128, 256, 0, stream>>>(part, inv_n);
  normconv_kernel<<<4096, 256, 0, stream>>>(x, y, inv_n, xnb, ynb);
  gemm_corr_kernel<<<dim3(64, 64), 256, 0, stream>>>(xnb, ynb, corr_top, rowmax_prt, colsum_prt);
  reduce_both_kernel<<<64, 256, 0, stream>>>(rowmax_prt, colsum_prt, out, inv_s);
  warped_kernel<<<256, 256, 0, stream>>>(corr_top, inv_s, ynb, out);
}

// Round 10
// 82.878 us; speedup vs baseline: 1.4113x; 1.4113x over previous
//
#include <hip/hip_runtime.h>
#include <hip/hip_bf16.h>

#define NN 8192
#define CC 256
// exp(x/0.01) = exp2(x * 100 * log2(e))
#define ESCALE 144.26950408889634f

typedef __attribute__((ext_vector_type(8))) short short8;
typedef __attribute__((ext_vector_type(4))) float f32x4;

typedef __attribute__((address_space(3))) unsigned int lds_u32;
typedef __attribute__((address_space(1))) const unsigned int glb_u32;

__device__ __forceinline__ void gload16(const ushort* g, ushort* l) {
  __builtin_amdgcn_global_load_lds((glb_u32*)(const void*)g, (lds_u32*)(void*)l, 16, 0, 0);
}

// ---------------- per-channel sum of squares (partials) ----------------
__global__ void colsumsq_kernel(const float* __restrict__ x, const float* __restrict__ y,
                                float* __restrict__ part) {
  const int b = blockIdx.x, t = threadIdx.x;
  const float* src = (b < 256) ? x : y;
  const int bb = b & 255;
  float s = 0.f;
#pragma unroll 4
  for (int r = 0; r < 32; ++r) {
    float v = src[(size_t)(bb * 32 + r) * CC + t];
    s = fmaf(v, v, s);
  }
  part[b * CC + t] = s;
}

// one wave per output norm: 512 outputs = 128 blocks x 4 waves
__global__ void finnorm_kernel(const float* __restrict__ part, float* __restrict__ inv_n) {
  const int g = blockIdx.x * 4 + (threadIdx.x >> 6);  // 0..511
  const int lane = threadIdx.x & 63;
  const int c = g & 255, T = g >> 8;
  float s = 0.f;
#pragma unroll
  for (int r = 0; r < 4; ++r)
    s += part[(size_t)((T << 8) + lane * 4 + r) * CC + c];
#pragma unroll
  for (int d = 1; d < 64; d <<= 1) s += __shfl_xor(s, d);
  if (lane == 0) inv_n[g] = 1.0f / sqrtf(s);
}

// ---------------- normalize + convert to bf16 (x and y fused) ----------------
__global__ void normconv_kernel(const float* __restrict__ x, const float* __restrict__ y,
                                const float* __restrict__ inv_n,
                                ushort* __restrict__ xnb, ushort* __restrict__ ynb) {
  int b = blockIdx.x;
  const float* src; ushort* dst; const float* inv;
  if (b < 2048) { src = x; dst = xnb; inv = inv_n; }
  else          { src = y; dst = ynb; inv = inv_n + 256; b -= 2048; }
  const int idx = (b * 256 + threadIdx.x) * 4;
  const float4 v = *(const float4*)(src + idx);
  const int c = idx & (CC - 1);
  __hip_bfloat16 h0 = __float2bfloat16(v.x * inv[c + 0]);
  __hip_bfloat16 h1 = __float2bfloat16(v.y * inv[c + 1]);
  __hip_bfloat16 h2 = __float2bfloat16(v.z * inv[c + 2]);
  __hip_bfloat16 h3 = __float2bfloat16(v.w * inv[c + 3]);
  ushort4 o;
  o.x = *(ushort*)&h0; o.y = *(ushort*)&h1; o.z = *(ushort*)&h2; o.w = *(ushort*)&h3;
  *(ushort4*)(dst + idx) = o;
}

// ---------------- main GEMM + fused epilogue ----------------
// 128x128 tile, 4 waves (2x2), BK=32, mfma_f32_16x16x32_bf16.
// Round-2 structure (best measured: 66.5us) with launch_bounds(256,4) to
// raise co-resident blocks/CU (hides the syncthreads vmcnt-drain stall).
__global__ __launch_bounds__(256, 4)
void gemm_corr_kernel(const ushort* __restrict__ Xn, const ushort* __restrict__ Yn,
                      float* __restrict__ corr_top,     // [256][NN]
                      float* __restrict__ rowmax_part,  // [64][NN]  idx cb*NN + i
                      float* __restrict__ colsum_part)  // [64][NN]  idx rb*NN + j
{
  const int cb = blockIdx.x, rb = blockIdx.y;
  const int tid = threadIdx.x;
  const int lane = tid & 63, wid = tid >> 6;
  const int wr = wid >> 1, wc = wid & 1;
  const int q = lane >> 4;    // k-group selector
  const int lr = lane & 15;

  __shared__ __align__(16) ushort As[128 * 32];
  __shared__ __align__(16) ushort Bs[128 * 32];
  __shared__ float redbuf[2][128];

  f32x4 acc[4][4];
#pragma unroll
  for (int m = 0; m < 4; ++m)
#pragma unroll
    for (int n = 0; n < 4; ++n) acc[m][n] = (f32x4){0.f, 0.f, 0.f, 0.f};

  // staging: chunk = r*256 + wid*64 + lane; row = chunk>>2; cq = chunk&3
  const int l2 = lane >> 2, cq = lane & 3;
  const size_t gA0 = (size_t)(rb * 128 +      wid * 16 + l2) * CC + cq * 8;
  const size_t gA1 = (size_t)(rb * 128 + 64 + wid * 16 + l2) * CC + cq * 8;
  const size_t gB0 = (size_t)(cb * 128 +      wid * 16 + l2) * CC + cq * 8;
  const size_t gB1 = (size_t)(cb * 128 + 64 + wid * 16 + l2) * CC + cq * 8;
  ushort* lA0 = As + wid * 512;
  ushort* lA1 = As + 2048 + wid * 512;
  ushort* lB0 = Bs + wid * 512;
  ushort* lB1 = Bs + 2048 + wid * 512;

  for (int kk = 0; kk < CC; kk += 32) {
    gload16(Xn + gA0 + kk, lA0);
    gload16(Xn + gA1 + kk, lA1);
    gload16(Yn + gB0 + kk, lB0);
    gload16(Yn + gB1 + kk, lB1);
    __syncthreads();   // drains vmcnt -> tiles resident

    short8 af[4], bf[4];
#pragma unroll
    for (int m = 0; m < 4; ++m)
      af[m] = *(const short8*)(&As[(wr * 64 + m * 16 + lr) * 32 + q * 8]);
#pragma unroll
    for (int n = 0; n < 4; ++n)
      bf[n] = *(const short8*)(&Bs[(wc * 64 + n * 16 + lr) * 32 + q * 8]);

#pragma unroll
    for (int m = 0; m < 4; ++m)
#pragma unroll
      for (int n = 0; n < 4; ++n)
        acc[m][n] = __builtin_amdgcn_mfma_f32_16x16x32_bf16(af[m], bf[n], acc[m][n], 0, 0, 0);
    __syncthreads();   // reads done before next overwrite
  }

  // ---- store top-256 corr rows for the warped pass ----
  if (rb < 2) {
    const int colg = cb * 128 + wc * 64 + lr;
#pragma unroll
    for (int m = 0; m < 4; ++m) {
      const int rowg = rb * 128 + wr * 64 + m * 16 + q * 4;
#pragma unroll
      for (int n = 0; n < 4; ++n)
#pragma unroll
        for (int r = 0; r < 4; ++r)
          corr_top[(size_t)(rowg + r) * NN + colg + n * 16] = acc[m][n][r];
    }
  }

  // ---- row max over this block's 128 columns ----
  // C/D layout: col = n*16 + (lane&15); row = m*16 + (lane>>4)*4 + r
#pragma unroll
  for (int m = 0; m < 4; ++m)
#pragma unroll
    for (int r = 0; r < 4; ++r) {
      float t = fmaxf(fmaxf(acc[m][0][r], acc[m][1][r]), fmaxf(acc[m][2][r], acc[m][3][r]));
      t = fmaxf(t, __shfl_xor(t, 1));
      t = fmaxf(t, __shfl_xor(t, 2));
      t = fmaxf(t, __shfl_xor(t, 4));
      t = fmaxf(t, __shfl_xor(t, 8));
      if (lr == 0) redbuf[wc][wr * 64 + m * 16 + q * 4 + r] = t;
    }
  __syncthreads();
  if (tid < 128)
    rowmax_part[(size_t)cb * NN + rb * 128 + tid] = fmaxf(redbuf[0][tid], redbuf[1][tid]);
  __syncthreads();

  // ---- column sum of exp(corr/tau) over this block's 128 rows ----
#pragma unroll
  for (int n = 0; n < 4; ++n) {
    float s = 0.f;
#pragma unroll
    for (int m = 0; m < 4; ++m)
#pragma unroll
      for (int r = 0; r < 4; ++r)
        s += __builtin_amdgcn_exp2f(acc[m][n][r] * ESCALE);
    s += __shfl_xor(s, 16);
    s += __shfl_xor(s, 32);
    if (lane < 16) redbuf[wr][wc * 64 + n * 16 + lr] = s;
  }
  __syncthreads();
  if (tid < 128)
    colsum_part[(size_t)rb * NN + cb * 128 + tid] = redbuf[0][tid] + redbuf[1][tid];
}

// ---------------- fused reductions: thread per output, coalesced ----------------
__global__ void reduce_both_kernel(const float* __restrict__ rowmax_part,
                                   const float* __restrict__ colsum_part,
                                   float* __restrict__ out, float* __restrict__ inv_s) {
  const int g = blockIdx.x * 256 + threadIdx.x;   // [0, 16384)
  if (g < 8192) {
    float m = -3.4e38f;
#pragma unroll
    for (int b = 0; b < 64; ++b) m = fmaxf(m, rowmax_part[(size_t)b * NN + g]);
    out[256 + g] = m;
  } else {
    const int j = g - 8192;
    float s = 0.f;
#pragma unroll
    for (int b = 0; b < 64; ++b) s += colsum_part[(size_t)b * NN + j];
    inv_s[j] = 1.0f / s;
  }
}

// ---------------- warped color partials ----------------
// 128 blocks = 32 k-octets x 4 j-quarters. Thread t: kk = t&7, j-stream t>>3.
// 8 adjacent lanes share j -> ynb reads are 16B-contiguous per 8 lanes.
__global__ void warped_kernel(const float* __restrict__ corr_top, const float* __restrict__ inv_s,
                              const ushort* __restrict__ ynb, float* __restrict__ wpart) {
  const int b = blockIdx.x;
  const int kb = b & 31, jb = b >> 5;
  const int k0 = kb * 8;
  const int t = threadIdx.x;
  const int kk = t & 7, js = t >> 3;     // js 0..31
  const int jbase = jb * 2048 + js;
  float p = 0.f;
#pragma unroll 4
  for (int i = 0; i < 64; ++i) {
    const int j = jbase + 32 * i;
    float c = corr_top[(size_t)(k0 + kk) * NN + j];
    float yv = __uint_as_float((unsigned)ynb[(size_t)j * CC + k0 + kk] << 16);
    p += __builtin_amdgcn_exp2f(c * ESCALE) * inv_s[j] * yv;
  }
  // reduce the 8 j-streams within each wave (kk preserved: masks 8,16,32)
  p += __shfl_xor(p, 8);
  p += __shfl_xor(p, 16);
  p += __shfl_xor(p, 32);
  __shared__ float lw[4][8];
  const int lane = t & 63, wid = t >> 6;
  if (lane < 8) lw[wid][lane] = p;
  __syncthreads();
  if (t < 8) wpart[jb * 256 + k0 + t] = lw[0][t] + lw[1][t] + lw[2][t] + lw[3][t];
}

__global__ void warpedfin_kernel(const float* __restrict__ wpart, float* __restrict__ out) {
  const int k = threadIdx.x;
  out[k] = wpart[k] + wpart[256 + k] + wpart[512 + k] + wpart[768 + k];
}

extern "C" void kernel_launch(void* const* d_in, const int* in_sizes, int n_in,
                              void* d_out, int out_size, void* d_ws, size_t ws_size,
                              hipStream_t stream) {
  const float* x = (const float*)d_in[0];
  const float* y = (const float*)d_in[1];
  float* out = (float*)d_out;
  char* ws = (char*)d_ws;

  ushort* xnb        = (ushort*)(ws);                        // 4 MB
  ushort* ynb        = (ushort*)(ws + (4u << 20));           // 4 MB
  float*  corr_top   = (float*)(ws + (8u << 20));            // 8 MB
  float*  rowmax_prt = (float*)(ws + (16u << 20));           // 2 MB
  float*  colsum_prt = (float*)(ws + (18u << 20));           // 2 MB
  float*  part       = (float*)(ws + (20u << 20));           // 512 KB (reused as wpart)
  float*  inv_n      = (float*)(ws + (20u << 20) + 524288);  // 2 KB
  float*  inv_s      = (float*)(ws + (20u << 20) + 524288 + 4096); // 32 KB

  colsumsq_kernel<<<512, 256, 0, stream>>>(x, y, part);
  finnorm_kernel<<<128, 256, 0, stream>>>(part, inv_n);
  normconv_kernel<<<4096, 256, 0, stream>>>(x, y, inv_n, xnb, ynb);
  gemm_corr_kernel<<<dim3(64, 64), 256, 0, stream>>>(xnb, ynb, corr_top, rowmax_prt, colsum_prt);
  reduce_both_kernel<<<64, 256, 0, stream>>>(rowmax_prt, colsum_prt, out, inv_s);
  warped_kernel<<<128, 256, 0, stream>>>(corr_top, inv_s, ynb, part);
  warpedfin_kernel<<<1, 256, 0, stream>>>(part, out);
}